// Round 7
// baseline (451.315 us; speedup 1.0000x reference)
//
#include <hip/hip_runtime.h>

#define BATCH 512
#define V 6890
#define NJ 24
#define VH (V/2)   // 3445 float2 per feature row

#define SD_N (V*30)
#define VT_N (V*3)
#define W_N  (V*24)
#define TOT_PK (SD_N+VT_N+W_N)          // 392730 floats
#define PREP_BLOCKS ((TOT_PK+255)/256)  // 1535
#define NCH 8
#define JREG_BLOCKS (NJ*NCH)            // 192
#define CH_SZ ((V+NCH-1)/NCH)           // 862

// workspace layout (float indices)
#define JP_OFF  0        // 192*33 jreg partials: [(ch*NJ+j)*33 + m]
#define PK_OFF  8192     // transposed fp32, rows stride V:
                         //   sd row f at f*V; vt row k at (30+k)*V; W row n at (33+n)*V

__device__ const int d_par[NJ] = {-1,0,0,0,1,2,3,4,5,6,7,8,9,9,9,12,13,14,16,17,18,19,20,21};

// ---------------- fused: transpose + chunked joint-regressor (partials) --------------
__global__ __launch_bounds__(256) void prepjreg_k(
    const float* __restrict__ sd, const float* __restrict__ vt, const float* __restrict__ W,
    const float* __restrict__ Jr,
    float* __restrict__ dst, float* __restrict__ JP)
{
  __shared__ float red[4*33];
  const int bid = blockIdx.x;
  const int t = threadIdx.x;
  if (bid < PREP_BLOCKS){
    int i = bid*256 + t;
    if (i >= TOT_PK) return;
    float val;
    if (i < SD_N){ int j=i/V, v=i-j*V; val = sd[v*30+j]; }
    else if (i < SD_N+VT_N){ int o=i-SD_N; int j=o/V, v=o-j*V; val = vt[v*3+j]; }
    else { int o=i-SD_N-VT_N; int j=o/V, v=o-j*V; val = W[v*24+j]; }
    dst[i] = val;
    return;
  }
  const int r  = bid - PREP_BLOCKS;   // r = ch*NJ + j
  const int j  = r % NJ;
  const int v0 = (r / NJ)*CH_SZ;
  const int v1 = (v0+CH_SZ < V) ? v0+CH_SZ : V;
  float acc[33];
#pragma unroll
  for (int m=0;m<33;m++) acc[m]=0.f;
  for (int v=v0+t; v<v1; v+=256){
    const float jr = Jr[j*V+v];
    const float* __restrict__ vp = vt + v*3;
    acc[0] = fmaf(jr, vp[0], acc[0]);
    acc[1] = fmaf(jr, vp[1], acc[1]);
    acc[2] = fmaf(jr, vp[2], acc[2]);
    const float2* __restrict__ sp = (const float2*)(sd + v*30);  // 120B stride, 8B aligned
#pragma unroll
    for (int m=0;m<15;m++){
      const float2 s = sp[m];
      acc[3+2*m]   = fmaf(jr, s.x, acc[3+2*m]);
      acc[3+2*m+1] = fmaf(jr, s.y, acc[3+2*m+1]);
    }
  }
  const int lane = t & 63, wid = t >> 6;
#pragma unroll
  for (int m=0;m<33;m++){
    float x = acc[m];
    x += __shfl_xor(x, 1);
    x += __shfl_xor(x, 2);
    x += __shfl_xor(x, 4);
    x += __shfl_xor(x, 8);
    x += __shfl_xor(x, 16);
    x += __shfl_xor(x, 32);
    if (lane == 0) red[wid*33+m] = x;
  }
  __syncthreads();
  if (t < 33){
    JP[r*33 + t] = red[t] + red[33+t] + red[66+t] + red[99+t];
  }
}

// ---------------- fused batch-prep (LDS) + main LBS ----------------------------------
// grid (7, 256). Block (x, bg): LDS prologue builds skinning matrices A for batches
// {2bg, 2bg+1}, then runs the main LBS loop for vhtiles x and x+7 SEQUENTIALLY
// (unroll 1: full unroll interleaved both tiles' regs under the 64-VGPR cap -> spill,
//  FETCH/WRITE went to ~600 MB symmetric in round 6; round 2 failed identically).
__global__ __launch_bounds__(256, 8) void fused_k(
    const float* __restrict__ betas, const float* __restrict__ body_pose,
    const float* __restrict__ go, const float* __restrict__ transl,
    const float* __restrict__ JP, const float2* __restrict__ pk,
    float* __restrict__ out, float* __restrict__ jout)
{
  const int t  = threadIdx.x;
  const int ht = t & 127;          // tid within half
  const int q  = t >> 7;           // half = batch-within-pair
  const int bg = blockIdx.y;
  const int b  = bg*2 + q;

  __shared__ float lb[2][11];
  __shared__ float lJ[2][72];
  __shared__ float lL[2][NJ*12];
  __shared__ float lW[2][NJ*12];
  __shared__ float lA[NJ*24];      // [n][q][12], rows 48B -> float4-aligned

  // ---- prologue step 1: betas ----
  if (ht < 11) lb[q][ht] = betas[b*11 + ht];
  __syncthreads();

  // ---- step 2: rest joints lJ = b0*(JT + JS.beta), summed over 8 chunk partials ----
  if (ht < 72){
    const int j = ht/3, k = ht-3*j;
    float s = 0.f;
#pragma unroll
    for (int ch=0; ch<NCH; ch++){
      const float* __restrict__ jp = JP + (ch*NJ+j)*33;
      float ss = jp[k];
#pragma unroll
      for (int l=0;l<10;l++) ss = fmaf(lb[q][1+l], jp[3 + k*10 + l], ss);
      s += ss;
    }
    lJ[q][ht] = lb[q][0]*s;
  }
  __syncthreads();

  // ---- step 3: rodrigues + local transforms directly into lL ----
  if (ht < NJ){
    const int j = ht;
    float p0,p1,p2;
    if (j==0){ p0=go[b*3+0]; p1=go[b*3+1]; p2=go[b*3+2]; }
    else { int o=b*69+(j-1)*3; p0=body_pose[o]; p1=body_pose[o+1]; p2=body_pose[o+2]; }
    float a0=p0+1e-8f, a1=p1+1e-8f, a2=p2+1e-8f;
    float angle = sqrtf(a0*a0+a1*a1+a2*a2);
    float inv = 1.0f/angle;
    float rx=p0*inv, ry=p1*inv, rz=p2*inv;
    float sn = sinf(angle), cs = cosf(angle), mc = 1.0f-cs;
    float K[9] = {0.f,-rz,ry, rz,0.f,-rx, -ry,rx,0.f};
    float R[9];
#pragma unroll
    for (int r=0;r<3;r++)
#pragma unroll
      for (int c=0;c<3;c++){
        float kk = K[r*3+0]*K[0+c] + K[r*3+1]*K[3+c] + K[r*3+2]*K[6+c];
        float ident = (r==c)?1.0f:0.0f;
        R[r*3+c] = ident + sn*K[r*3+c] + mc*kk;
      }
    const int p = d_par[j];
    float* __restrict__ row = &lL[q][j*12];
    row[0]=R[0]; row[1]=R[1]; row[2]=R[2];
    row[4]=R[3]; row[5]=R[4]; row[6]=R[5];
    row[8]=R[6]; row[9]=R[7]; row[10]=R[8];
    row[3]  = (j==0) ? lJ[q][0] : lJ[q][j*3+0] - lJ[q][p*3+0];
    row[7]  = (j==0) ? lJ[q][1] : lJ[q][j*3+1] - lJ[q][p*3+1];
    row[11] = (j==0) ? lJ[q][2] : lJ[q][j*3+2] - lJ[q][p*3+2];
  }
  __syncthreads();

  // ---- step 4: kinematic chain (12 threads per half) ----
  if (ht < 12) lW[q][ht] = lL[q][ht];
  __syncthreads();
  for (int i=1;i<NJ;i++){
    if (ht < 12){
      const int p = d_par[i];
      const int r = ht>>2, c = ht&3;
      float s = lW[q][p*12+r*4+0]*lL[q][i*12+0+c]
              + lW[q][p*12+r*4+1]*lL[q][i*12+4+c]
              + lW[q][p*12+r*4+2]*lL[q][i*12+8+c];
      if (c==3) s += lW[q][p*12+r*4+3];
      lW[q][i*12+ht] = s;
    }
    __syncthreads();
  }

  // ---- step 5: J_transformed (only one block column writes) ----
  if (blockIdx.x == 0 && ht < 72){
    const int j = ht/3, k = ht-3*j;
    jout[b*72 + ht] = lW[q][j*12 + k*4 + 3];
  }

  // ---- step 6: A = world with t-col -= R_world @ J_rest, packed [n][q][12] ----
  for (int idx=t; idx<NJ*24; idx+=256){
    const int n = idx/24, rem = idx-24*n, qq = rem/12, rc = rem-12*qq;
    const int r = rc>>2, c = rc&3;
    float val = lW[qq][n*12+rc];
    if (c==3){
      val -= lW[qq][n*12+r*4+0]*lJ[qq][n*3+0]
           + lW[qq][n*12+r*4+1]*lJ[qq][n*3+1]
           + lW[qq][n*12+r*4+2]*lJ[qq][n*3+2];
    }
    lA[n*24 + qq*12 + rc] = val;
  }
  __syncthreads();

  // ---- per-batch uniform scalars (block-uniform -> s_load / SGPR) ----
  float b0s[2], cf[2][10], tr[2][3];
#pragma unroll
  for (int qq=0;qq<2;qq++){
    const float* __restrict__ bp = betas + (bg*2+qq)*11;
    const float bb0 = bp[0];
    b0s[qq] = bb0;
#pragma unroll
    for (int l=0;l<10;l++) cf[qq][l] = bb0*bp[1+l];
    const float* __restrict__ tp = transl + (bg*2+qq)*3;
    tr[qq][0]=tp[0]; tr[qq][1]=tp[1]; tr[qq][2]=tp[2];
  }

  // ---- main LBS: two vh tiles per block, STRICTLY SEQUENTIAL ----
#pragma unroll 1
  for (int uu=0; uu<2; uu++){
    const int vhtile = blockIdx.x + uu*7;
    const int vh = vhtile*256 + t;
    if (vh < VH){
      const float2 vt0 = pk[30*VH + vh];
      const float2 vt1 = pk[31*VH + vh];
      const float2 vt2 = pk[32*VH + vh];

      float2 vs[2][3];
#pragma unroll
      for (int qq=0;qq<2;qq++){
        const float b0 = b0s[qq];
        vs[qq][0] = make_float2(b0*vt0.x, b0*vt0.y);
        vs[qq][1] = make_float2(b0*vt1.x, b0*vt1.y);
        vs[qq][2] = make_float2(b0*vt2.x, b0*vt2.y);
      }
#pragma unroll
      for (int l=0;l<10;l++){
        const float2 s0 = pk[(0*10+l)*VH + vh];
        const float2 s1 = pk[(1*10+l)*VH + vh];
        const float2 s2 = pk[(2*10+l)*VH + vh];
#pragma unroll
        for (int qq=0;qq<2;qq++){
          const float c = cf[qq][l];
          vs[qq][0].x = fmaf(c, s0.x, vs[qq][0].x); vs[qq][0].y = fmaf(c, s0.y, vs[qq][0].y);
          vs[qq][1].x = fmaf(c, s1.x, vs[qq][1].x); vs[qq][1].y = fmaf(c, s1.y, vs[qq][1].y);
          vs[qq][2].x = fmaf(c, s2.x, vs[qq][2].x); vs[qq][2].y = fmaf(c, s2.y, vs[qq][2].y);
        }
      }

      float y[2][6];
#pragma unroll
      for (int qq=0;qq<2;qq++)
#pragma unroll
        for (int i=0;i<6;i++) y[qq][i] = 0.f;

#pragma unroll 4
      for (int n=0;n<NJ;n++){
        const float2 w = pk[(33+n)*VH + vh];
#pragma unroll
        for (int qq=0;qq<2;qq++){
          const float4 A0 = *(const float4*)&lA[n*24+qq*12+0];   // uniform -> broadcast
          const float4 A1 = *(const float4*)&lA[n*24+qq*12+4];
          const float4 A2 = *(const float4*)&lA[n*24+qq*12+8];
          float tt;
          tt = fmaf(A0.z, vs[qq][2].x, fmaf(A0.y, vs[qq][1].x, fmaf(A0.x, vs[qq][0].x, A0.w)));
          y[qq][0] = fmaf(w.x, tt, y[qq][0]);
          tt = fmaf(A0.z, vs[qq][2].y, fmaf(A0.y, vs[qq][1].y, fmaf(A0.x, vs[qq][0].y, A0.w)));
          y[qq][1] = fmaf(w.y, tt, y[qq][1]);
          tt = fmaf(A1.z, vs[qq][2].x, fmaf(A1.y, vs[qq][1].x, fmaf(A1.x, vs[qq][0].x, A1.w)));
          y[qq][2] = fmaf(w.x, tt, y[qq][2]);
          tt = fmaf(A1.z, vs[qq][2].y, fmaf(A1.y, vs[qq][1].y, fmaf(A1.x, vs[qq][0].y, A1.w)));
          y[qq][3] = fmaf(w.y, tt, y[qq][3]);
          tt = fmaf(A2.z, vs[qq][2].x, fmaf(A2.y, vs[qq][1].x, fmaf(A2.x, vs[qq][0].x, A2.w)));
          y[qq][4] = fmaf(w.x, tt, y[qq][4]);
          tt = fmaf(A2.z, vs[qq][2].y, fmaf(A2.y, vs[qq][1].y, fmaf(A2.x, vs[qq][0].y, A2.w)));
          y[qq][5] = fmaf(w.y, tt, y[qq][5]);
        }
      }

      const int v0 = 2*vh;
#pragma unroll
      for (int qq=0;qq<2;qq++){
        const float t0 = tr[qq][0], t1 = tr[qq][1], t2 = tr[qq][2];
        const int bb = bg*2 + qq;
        float2* __restrict__ o2 = (float2*)(out + (bb*V + v0)*3);
        o2[0] = make_float2(y[qq][0]+t0, y[qq][2]+t1);
        o2[1] = make_float2(y[qq][4]+t2, y[qq][1]+t0);
        o2[2] = make_float2(y[qq][3]+t1, y[qq][5]+t2);
      }
    }
  }
}

extern "C" void kernel_launch(void* const* d_in, const int* in_sizes, int n_in,
                              void* d_out, int out_size, void* d_ws, size_t ws_size,
                              hipStream_t stream)
{
  const float* betas     = (const float*)d_in[0];
  const float* body_pose = (const float*)d_in[1];
  const float* go        = (const float*)d_in[2];
  const float* transl    = (const float*)d_in[3];
  const float* sdirs     = (const float*)d_in[4];
  const float* vtempl    = (const float*)d_in[5];
  const float* Jr        = (const float*)d_in[6];
  const float* lw        = (const float*)d_in[7];
  float* wsf = (float*)d_ws;
  float* out = (float*)d_out;

  hipLaunchKernelGGL(prepjreg_k, dim3(PREP_BLOCKS + JREG_BLOCKS), dim3(256), 0, stream,
                     sdirs, vtempl, lw, Jr, wsf+PK_OFF, wsf+JP_OFF);
  hipLaunchKernelGGL(fused_k, dim3(7, 256), dim3(256), 0, stream,
                     betas, body_pose, go, transl, wsf+JP_OFF,
                     (const float2*)(wsf+PK_OFF), out, out + BATCH*V*3);
}

// Round 8
// 197.724 us; speedup vs baseline: 2.2826x; 2.2826x over previous
//
#include <hip/hip_runtime.h>

#define BATCH 512
#define V 6890
#define NJ 24
#define VH (V/2)   // 3445 float2 per feature row

#define SD_N (V*30)
#define VT_N (V*3)
#define W_N  (V*24)
#define TOT_PK (SD_N+VT_N+W_N)          // 392730 floats
#define PREP_BLOCKS ((TOT_PK+255)/256)  // 1535
#define NCH 8
#define JREG_BLOCKS (NJ*NCH)            // 192
#define CH_SZ ((V+NCH-1)/NCH)           // 862

// workspace layout (float indices)
// A layout: 256 groups of 2 batches: off = (b>>1)*576 + n*24 + (b&1)*12 + rc
#define A_OFF   0          // BATCH*288 fp32 skinning matrices (pair-grouped)
#define BS_OFF  147456     // BATCH*16 per-batch scalars {b0, b0*beta[1..10], transl[0..2], pad}
#define JP_OFF  155648     // 192*33 jreg partials: [(ch*NJ+j)*33 + m]
#define PK_OFF  162048     // transposed fp32, rows stride V:
                           //   sd row f at f*V; vt row k at (30+k)*V; W row n at (33+n)*V

__device__ const int d_par[NJ] = {-1,0,0,0,1,2,3,4,5,6,7,8,9,9,9,12,13,14,16,17,18,19,20,21};

// ---------------- fused: transpose + chunked joint-regressor (partials) --------------
__global__ __launch_bounds__(256) void prepjreg_k(
    const float* __restrict__ sd, const float* __restrict__ vt, const float* __restrict__ W,
    const float* __restrict__ Jr,
    float* __restrict__ dst, float* __restrict__ JP)
{
  __shared__ float red[4*33];
  const int bid = blockIdx.x;
  const int t = threadIdx.x;
  if (bid < PREP_BLOCKS){
    int i = bid*256 + t;
    if (i >= TOT_PK) return;
    float val;
    if (i < SD_N){ int j=i/V, v=i-j*V; val = sd[v*30+j]; }
    else if (i < SD_N+VT_N){ int o=i-SD_N; int j=o/V, v=o-j*V; val = vt[v*3+j]; }
    else { int o=i-SD_N-VT_N; int j=o/V, v=o-j*V; val = W[v*24+j]; }
    dst[i] = val;
    return;
  }
  const int r  = bid - PREP_BLOCKS;   // r = ch*NJ + j
  const int j  = r % NJ;
  const int v0 = (r / NJ)*CH_SZ;
  const int v1 = (v0+CH_SZ < V) ? v0+CH_SZ : V;
  float acc[33];
#pragma unroll
  for (int m=0;m<33;m++) acc[m]=0.f;
  for (int v=v0+t; v<v1; v+=256){
    const float jr = Jr[j*V+v];
    const float* __restrict__ vp = vt + v*3;
    acc[0] = fmaf(jr, vp[0], acc[0]);
    acc[1] = fmaf(jr, vp[1], acc[1]);
    acc[2] = fmaf(jr, vp[2], acc[2]);
    const float2* __restrict__ sp = (const float2*)(sd + v*30);  // 120B stride, 8B aligned
#pragma unroll
    for (int m=0;m<15;m++){
      const float2 s = sp[m];
      acc[3+2*m]   = fmaf(jr, s.x, acc[3+2*m]);
      acc[3+2*m+1] = fmaf(jr, s.y, acc[3+2*m+1]);
    }
  }
  const int lane = t & 63, wid = t >> 6;
#pragma unroll
  for (int m=0;m<33;m++){
    float x = acc[m];
    x += __shfl_xor(x, 1);
    x += __shfl_xor(x, 2);
    x += __shfl_xor(x, 4);
    x += __shfl_xor(x, 8);
    x += __shfl_xor(x, 16);
    x += __shfl_xor(x, 32);
    if (lane == 0) red[wid*33+m] = x;
  }
  __syncthreads();
  if (t < 33){
    JP[r*33 + t] = red[t] + red[33+t] + red[66+t] + red[99+t];
  }
}

// ---------------- per-batch: joints, rodrigues, chain, A (pair-grouped), J_out -------
__global__ __launch_bounds__(64) void batch_k(
    const float* __restrict__ betas, const float* __restrict__ body_pose,
    const float* __restrict__ go, const float* __restrict__ transl,
    const float* __restrict__ JP,
    float* __restrict__ A, float* __restrict__ bsc, float* __restrict__ jout)
{
  const int b = blockIdx.x;
  const int t = threadIdx.x;
  __shared__ float lb[11];
  __shared__ float lJ[72];
  __shared__ float lR[NJ*9];
  __shared__ float lL[NJ*12];
  __shared__ float lW[NJ*12];
  if (t < 11) lb[t] = betas[b*11+t];
  __syncthreads();
  const float b0 = lb[0];
  for (int idx=t; idx<72; idx+=64){
    const int j = idx/3, k = idx-3*j;
    float s = 0.f;
#pragma unroll
    for (int ch=0; ch<NCH; ch++){
      const float* __restrict__ jp = JP + (ch*NJ+j)*33;
      float ss = jp[k];
#pragma unroll
      for (int l=0;l<10;l++) ss = fmaf(lb[1+l], jp[3 + k*10 + l], ss);
      s += ss;
    }
    lJ[idx] = b0*s;
  }
  if (t==0) bsc[b*16] = b0;
  if (t>=1 && t<11) bsc[b*16+t] = b0*lb[t];
  if (t<3) bsc[b*16+11+t] = transl[b*3+t];
  if (t < NJ){
    float p0,p1,p2;
    if (t==0){ p0=go[b*3+0]; p1=go[b*3+1]; p2=go[b*3+2]; }
    else { int o=b*69+(t-1)*3; p0=body_pose[o]; p1=body_pose[o+1]; p2=body_pose[o+2]; }
    float a0=p0+1e-8f, a1=p1+1e-8f, a2=p2+1e-8f;
    float angle = sqrtf(a0*a0+a1*a1+a2*a2);
    float inv = 1.0f/angle;
    float rx=p0*inv, ry=p1*inv, rz=p2*inv;
    float sn = sinf(angle), cs = cosf(angle), mc = 1.0f-cs;
    float K[9] = {0.f,-rz,ry, rz,0.f,-rx, -ry,rx,0.f};
    float KK[9];
    #pragma unroll
    for (int r=0;r<3;r++)
      #pragma unroll
      for (int c=0;c<3;c++)
        KK[r*3+c] = K[r*3+0]*K[0+c] + K[r*3+1]*K[3+c] + K[r*3+2]*K[6+c];
    #pragma unroll
    for (int e=0;e<9;e++){
      float ident = (e==0||e==4||e==8)?1.0f:0.0f;
      lR[t*9+e] = ident + sn*K[e] + mc*KK[e];
    }
  }
  __syncthreads();
  for (int idx=t; idx<288; idx+=64){
    int j = idx/12, rc = idx-12*j, r = rc>>2, c = rc&3;
    float val;
    if (c<3) val = lR[j*9 + r*3 + c];
    else {
      int p = (j==0) ? 0 : d_par[j];
      val = (j==0) ? lJ[r] : (lJ[j*3+r] - lJ[p*3+r]);
    }
    lL[idx] = val;
  }
  __syncthreads();
  if (t<12) lW[t] = lL[t];
  __syncthreads();
  for (int i=1;i<NJ;i++){
    if (t<12){
      int p = d_par[i];
      int r = t>>2, c = t&3;
      float s = lW[p*12+r*4+0]*lL[i*12+0+c]
              + lW[p*12+r*4+1]*lL[i*12+4+c]
              + lW[p*12+r*4+2]*lL[i*12+8+c];
      if (c==3) s += lW[p*12+r*4+3];
      lW[i*12+t] = s;
    }
    __syncthreads();
  }
  for (int idx=t; idx<72; idx+=64){
    int j=idx/3, k=idx-3*j;
    jout[b*72+idx] = lW[j*12+k*4+3];
  }
  // A (pair-grouped layout) = world with t-col -= R_world @ J
  const int g = b>>1, q = b&1;
  float* __restrict__ Ab = A + g*576 + q*12;
  for (int idx=t; idx<288; idx+=64){
    int n=idx/12, rc=idx-12*n, r=rc>>2, c=rc&3;
    float val = lW[n*12+rc];
    if (c==3){
      val -= lW[n*12+r*4+0]*lJ[n*3+0] + lW[n*12+r*4+1]*lJ[n*3+1] + lW[n*12+r*4+2]*lJ[n*3+2];
    }
    Ab[n*24 + rc] = val;
  }
}

// ---------------- main LBS: grid (14,128); each block runs TWO batch-pairs -----------
// bg = 2*blockIdx.y + gg, sequential (unroll 1 -> same registers reused; the two tiles
// read the SAME pk rows, second pass L1-hot). 1792 blocks = exactly 7/CU: one uniform
// co-resident generation, no ragged tail (round-3's 14/CU ran as 8+6).
__global__ __launch_bounds__(256, 8) void main_k(
    const float* __restrict__ A, const float* __restrict__ bsc,
    const float2* __restrict__ pk, float* __restrict__ out)
{
  const int vh = blockIdx.x*256 + threadIdx.x;
  if (vh >= VH) return;

#pragma unroll 1
  for (int gg=0; gg<2; ++gg){
    const int bg = blockIdx.y*2 + gg;          // batch pair (shared by block)
    const float* __restrict__ Ag = A + bg*576;
    const float* __restrict__ bs = bsc + bg*32;

    const float2 vt0 = pk[30*VH + vh];
    const float2 vt1 = pk[31*VH + vh];
    const float2 vt2 = pk[32*VH + vh];

    float2 vs[2][3];
#pragma unroll
    for (int q=0;q<2;q++){
      const float b0 = bs[q*16];
      vs[q][0] = make_float2(b0*vt0.x, b0*vt0.y);
      vs[q][1] = make_float2(b0*vt1.x, b0*vt1.y);
      vs[q][2] = make_float2(b0*vt2.x, b0*vt2.y);
    }
#pragma unroll
    for (int l=0;l<10;l++){
      const float2 s0 = pk[(0*10+l)*VH + vh];
      const float2 s1 = pk[(1*10+l)*VH + vh];
      const float2 s2 = pk[(2*10+l)*VH + vh];
#pragma unroll
      for (int q=0;q<2;q++){
        const float c = bs[q*16+1+l];
        vs[q][0].x = fmaf(c, s0.x, vs[q][0].x); vs[q][0].y = fmaf(c, s0.y, vs[q][0].y);
        vs[q][1].x = fmaf(c, s1.x, vs[q][1].x); vs[q][1].y = fmaf(c, s1.y, vs[q][1].y);
        vs[q][2].x = fmaf(c, s2.x, vs[q][2].x); vs[q][2].y = fmaf(c, s2.y, vs[q][2].y);
      }
    }

    float y[2][6];
#pragma unroll
    for (int q=0;q<2;q++)
#pragma unroll
      for (int i=0;i<6;i++) y[q][i] = 0.f;

#pragma unroll 4
    for (int n=0;n<NJ;n++){
      const float2 w = pk[(33+n)*VH + vh];
#pragma unroll
      for (int q=0;q<2;q++){
        const float* __restrict__ an = Ag + n*24 + q*12;   // block-uniform -> s_load
        float tt;
        tt = fmaf(an[2], vs[q][2].x, fmaf(an[1], vs[q][1].x, fmaf(an[0], vs[q][0].x, an[3])));
        y[q][0] = fmaf(w.x, tt, y[q][0]);
        tt = fmaf(an[2], vs[q][2].y, fmaf(an[1], vs[q][1].y, fmaf(an[0], vs[q][0].y, an[3])));
        y[q][1] = fmaf(w.y, tt, y[q][1]);
        tt = fmaf(an[6], vs[q][2].x, fmaf(an[5], vs[q][1].x, fmaf(an[4], vs[q][0].x, an[7])));
        y[q][2] = fmaf(w.x, tt, y[q][2]);
        tt = fmaf(an[6], vs[q][2].y, fmaf(an[5], vs[q][1].y, fmaf(an[4], vs[q][0].y, an[7])));
        y[q][3] = fmaf(w.y, tt, y[q][3]);
        tt = fmaf(an[10], vs[q][2].x, fmaf(an[9], vs[q][1].x, fmaf(an[8], vs[q][0].x, an[11])));
        y[q][4] = fmaf(w.x, tt, y[q][4]);
        tt = fmaf(an[10], vs[q][2].y, fmaf(an[9], vs[q][1].y, fmaf(an[8], vs[q][0].y, an[11])));
        y[q][5] = fmaf(w.y, tt, y[q][5]);
      }
    }

    const int v0 = 2*vh;
#pragma unroll
    for (int q=0;q<2;q++){
      const float t0 = bs[q*16+11], t1 = bs[q*16+12], t2 = bs[q*16+13];
      const int b = bg*2 + q;
      float2* __restrict__ o2 = (float2*)(out + (b*V + v0)*3);
      o2[0] = make_float2(y[q][0]+t0, y[q][2]+t1);
      o2[1] = make_float2(y[q][4]+t2, y[q][1]+t0);
      o2[2] = make_float2(y[q][3]+t1, y[q][5]+t2);
    }
  }
}

extern "C" void kernel_launch(void* const* d_in, const int* in_sizes, int n_in,
                              void* d_out, int out_size, void* d_ws, size_t ws_size,
                              hipStream_t stream)
{
  const float* betas     = (const float*)d_in[0];
  const float* body_pose = (const float*)d_in[1];
  const float* go        = (const float*)d_in[2];
  const float* transl    = (const float*)d_in[3];
  const float* sdirs     = (const float*)d_in[4];
  const float* vtempl    = (const float*)d_in[5];
  const float* Jr        = (const float*)d_in[6];
  const float* lw        = (const float*)d_in[7];
  float* wsf = (float*)d_ws;
  float* out = (float*)d_out;

  hipLaunchKernelGGL(prepjreg_k, dim3(PREP_BLOCKS + JREG_BLOCKS), dim3(256), 0, stream,
                     sdirs, vtempl, lw, Jr, wsf+PK_OFF, wsf+JP_OFF);
  hipLaunchKernelGGL(batch_k, dim3(BATCH), dim3(64), 0, stream,
                     betas, body_pose, go, transl, wsf+JP_OFF,
                     wsf+A_OFF, wsf+BS_OFF, out + BATCH*V*3);
  hipLaunchKernelGGL(main_k, dim3((VH+255)/256, BATCH/4), dim3(256), 0, stream,
                     wsf+A_OFF, wsf+BS_OFF, (const float2*)(wsf+PK_OFF), out);
}

// Round 9
// 139.005 us; speedup vs baseline: 3.2468x; 1.4224x over previous
//
#include <hip/hip_runtime.h>

#define BATCH 512
#define V 6890
#define NJ 24
#define VH (V/2)   // 3445 vertex-pairs

#define NCH 8
#define JREG_BLOCKS (NJ*NCH)            // 192
#define CH_SZ ((V+NCH-1)/NCH)           // 862

// paired-row pk4 layout: 29 float4 rows of length VH.
//   pair p<15 : sd features (2p, 2p+1)            [sd feature j = k*10+l]
//   pair 15   : vt0, vt1
//   pair 16   : vt2, pad(0)
//   pair 17+np: W joints (2np, 2np+1)
// element: pk4[p*VH+vh] = { r0[2vh], r0[2vh+1], r1[2vh], r1[2vh+1] }
#define NPAIR 29
#define N4 (NPAIR*VH)                    // 99905 float4 elements
#define PREP4_BLOCKS ((N4+255)/256)      // 391

// workspace layout (float indices)
// A layout: 256 groups of 2 batches: off = (b>>1)*576 + n*24 + (b&1)*12 + rc
#define A_OFF   0          // BATCH*288 fp32 skinning matrices (pair-grouped)
#define BS_OFF  147456     // BATCH*16 per-batch scalars {b0, b0*beta[1..10], transl[0..2], pad}
#define JP_OFF  155648     // 192*33 jreg partials: [(ch*NJ+j)*33 + m]
#define PK_OFF  162048     // float4-paired pk4 (byte offset 648192, 16B-aligned)

__device__ const int d_par[NJ] = {-1,0,0,0,1,2,3,4,5,6,7,8,9,9,9,12,13,14,16,17,18,19,20,21};

// ---------------- fused: float4-paired transpose + chunked joint-regressor -----------
__global__ __launch_bounds__(256) void prepjreg_k(
    const float* __restrict__ sd, const float* __restrict__ vt, const float* __restrict__ W,
    const float* __restrict__ Jr,
    float4* __restrict__ dst4, float* __restrict__ JP)
{
  __shared__ float red[4*33];
  const int bid = blockIdx.x;
  const int t = threadIdx.x;
  if (bid < PREP4_BLOCKS){
    const int i = bid*256 + t;
    if (i >= N4) return;
    const int p  = i / VH;
    const int vh = i - p*VH;
    const int v0 = 2*vh;
    float4 o;
    if (p < 15){                      // sd rows (2p, 2p+1): adjacent -> float2 per vertex
      const float2 a = *(const float2*)(sd + v0*30     + 2*p);
      const float2 b = *(const float2*)(sd + (v0+1)*30 + 2*p);
      o = make_float4(a.x, b.x, a.y, b.y);
    } else if (p == 15){              // vt0, vt1
      const float2 a = *(const float2*)(vt + v0*3);       // v0 even -> 8B aligned
      const float  b0 = vt[(v0+1)*3], b1 = vt[(v0+1)*3+1];
      o = make_float4(a.x, b0, a.y, b1);
    } else if (p == 16){              // vt2, pad
      o = make_float4(vt[v0*3+2], vt[(v0+1)*3+2], 0.f, 0.f);
    } else {                          // W joints (2(p-17), 2(p-17)+1)
      const int n0 = 2*(p-17);
      const float2 a = *(const float2*)(W + v0*24     + n0);
      const float2 b = *(const float2*)(W + (v0+1)*24 + n0);
      o = make_float4(a.x, b.x, a.y, b.y);
    }
    dst4[i] = o;
    return;
  }
  // ---- jreg: (joint j, chunk ch) partial reduction -> JP (reads ORIGINAL layout) ----
  const int r  = bid - PREP4_BLOCKS;   // r = ch*NJ + j
  const int j  = r % NJ;
  const int v0 = (r / NJ)*CH_SZ;
  const int v1 = (v0+CH_SZ < V) ? v0+CH_SZ : V;
  float acc[33];
#pragma unroll
  for (int m=0;m<33;m++) acc[m]=0.f;
  for (int v=v0+t; v<v1; v+=256){
    const float jr = Jr[j*V+v];
    const float* __restrict__ vp = vt + v*3;
    acc[0] = fmaf(jr, vp[0], acc[0]);
    acc[1] = fmaf(jr, vp[1], acc[1]);
    acc[2] = fmaf(jr, vp[2], acc[2]);
    const float2* __restrict__ sp = (const float2*)(sd + v*30);  // 120B stride, 8B aligned
#pragma unroll
    for (int m=0;m<15;m++){
      const float2 s = sp[m];
      acc[3+2*m]   = fmaf(jr, s.x, acc[3+2*m]);
      acc[3+2*m+1] = fmaf(jr, s.y, acc[3+2*m+1]);
    }
  }
  const int lane = t & 63, wid = t >> 6;
#pragma unroll
  for (int m=0;m<33;m++){
    float x = acc[m];
    x += __shfl_xor(x, 1);
    x += __shfl_xor(x, 2);
    x += __shfl_xor(x, 4);
    x += __shfl_xor(x, 8);
    x += __shfl_xor(x, 16);
    x += __shfl_xor(x, 32);
    if (lane == 0) red[wid*33+m] = x;
  }
  __syncthreads();
  if (t < 33){
    JP[r*33 + t] = red[t] + red[33+t] + red[66+t] + red[99+t];
  }
}

// ---------------- per-batch: joints, rodrigues, chain, A (pair-grouped), J_out -------
__global__ __launch_bounds__(64) void batch_k(
    const float* __restrict__ betas, const float* __restrict__ body_pose,
    const float* __restrict__ go, const float* __restrict__ transl,
    const float* __restrict__ JP,
    float* __restrict__ A, float* __restrict__ bsc, float* __restrict__ jout)
{
  const int b = blockIdx.x;
  const int t = threadIdx.x;
  __shared__ float lb[11];
  __shared__ float lJ[72];
  __shared__ float lR[NJ*9];
  __shared__ float lL[NJ*12];
  __shared__ float lW[NJ*12];
  if (t < 11) lb[t] = betas[b*11+t];
  __syncthreads();
  const float b0 = lb[0];
  for (int idx=t; idx<72; idx+=64){
    const int j = idx/3, k = idx-3*j;
    float s = 0.f;
#pragma unroll
    for (int ch=0; ch<NCH; ch++){
      const float* __restrict__ jp = JP + (ch*NJ+j)*33;
      float ss = jp[k];
#pragma unroll
      for (int l=0;l<10;l++) ss = fmaf(lb[1+l], jp[3 + k*10 + l], ss);
      s += ss;
    }
    lJ[idx] = b0*s;
  }
  if (t==0) bsc[b*16] = b0;
  if (t>=1 && t<11) bsc[b*16+t] = b0*lb[t];
  if (t<3) bsc[b*16+11+t] = transl[b*3+t];
  if (t < NJ){
    float p0,p1,p2;
    if (t==0){ p0=go[b*3+0]; p1=go[b*3+1]; p2=go[b*3+2]; }
    else { int o=b*69+(t-1)*3; p0=body_pose[o]; p1=body_pose[o+1]; p2=body_pose[o+2]; }
    float a0=p0+1e-8f, a1=p1+1e-8f, a2=p2+1e-8f;
    float angle = sqrtf(a0*a0+a1*a1+a2*a2);
    float inv = 1.0f/angle;
    float rx=p0*inv, ry=p1*inv, rz=p2*inv;
    float sn = sinf(angle), cs = cosf(angle), mc = 1.0f-cs;
    float K[9] = {0.f,-rz,ry, rz,0.f,-rx, -ry,rx,0.f};
    float KK[9];
    #pragma unroll
    for (int r=0;r<3;r++)
      #pragma unroll
      for (int c=0;c<3;c++)
        KK[r*3+c] = K[r*3+0]*K[0+c] + K[r*3+1]*K[3+c] + K[r*3+2]*K[6+c];
    #pragma unroll
    for (int e=0;e<9;e++){
      float ident = (e==0||e==4||e==8)?1.0f:0.0f;
      lR[t*9+e] = ident + sn*K[e] + mc*KK[e];
    }
  }
  __syncthreads();
  for (int idx=t; idx<288; idx+=64){
    int j = idx/12, rc = idx-12*j, r = rc>>2, c = rc&3;
    float val;
    if (c<3) val = lR[j*9 + r*3 + c];
    else {
      int p = (j==0) ? 0 : d_par[j];
      val = (j==0) ? lJ[r] : (lJ[j*3+r] - lJ[p*3+r]);
    }
    lL[idx] = val;
  }
  __syncthreads();
  if (t<12) lW[t] = lL[t];
  __syncthreads();
  for (int i=1;i<NJ;i++){
    if (t<12){
      int p = d_par[i];
      int r = t>>2, c = t&3;
      float s = lW[p*12+r*4+0]*lL[i*12+0+c]
              + lW[p*12+r*4+1]*lL[i*12+4+c]
              + lW[p*12+r*4+2]*lL[i*12+8+c];
      if (c==3) s += lW[p*12+r*4+3];
      lW[i*12+t] = s;
    }
    __syncthreads();
  }
  for (int idx=t; idx<72; idx+=64){
    int j=idx/3, k=idx-3*j;
    jout[b*72+idx] = lW[j*12+k*4+3];
  }
  // A (pair-grouped layout) = world with t-col -= R_world @ J
  const int g = b>>1, q = b&1;
  float* __restrict__ Ab = A + g*576 + q*12;
  for (int idx=t; idx<288; idx+=64){
    int n=idx/12, rc=idx-12*n, r=rc>>2, c=rc&3;
    float val = lW[n*12+rc];
    if (c==3){
      val -= lW[n*12+r*4+0]*lJ[n*3+0] + lW[n*12+r*4+1]*lJ[n*3+1] + lW[n*12+r*4+2]*lJ[n*3+2];
    }
    Ab[n*24 + rc] = val;
  }
}

// ---------------- main LBS: round-3 shape, float4-paired pk (29 loads, was 57) -------
__global__ __launch_bounds__(256, 8) void main_k(
    const float* __restrict__ A, const float* __restrict__ bsc,
    const float4* __restrict__ pk4, float* __restrict__ out)
{
  const int vh = blockIdx.x*256 + threadIdx.x;
  if (vh >= VH) return;
  const int bg = blockIdx.y;                 // batch pair (shared by block)
  const float* __restrict__ Ag = A + bg*576;
  const float* __restrict__ bs = bsc + bg*32;

  const float4 vp0 = pk4[15*VH + vh];        // vt0(v0,v1), vt1(v0,v1)
  const float4 vp1 = pk4[16*VH + vh];        // vt2(v0,v1), pad

  float2 vs[2][3];
#pragma unroll
  for (int q=0;q<2;q++){
    const float b0 = bs[q*16];
    vs[q][0] = make_float2(b0*vp0.x, b0*vp0.y);
    vs[q][1] = make_float2(b0*vp0.z, b0*vp0.w);
    vs[q][2] = make_float2(b0*vp1.x, b0*vp1.y);
  }
#pragma unroll
  for (int lp=0; lp<5; lp++){
    const float4 P0 = pk4[(lp   )*VH + vh];  // k=0 rows (2lp, 2lp+1)
    const float4 P1 = pk4[(5+lp )*VH + vh];  // k=1 rows
    const float4 P2 = pk4[(10+lp)*VH + vh];  // k=2 rows
#pragma unroll
    for (int q=0;q<2;q++){
      const float c0 = bs[q*16+1+2*lp];
      const float c1 = bs[q*16+2+2*lp];
      vs[q][0].x = fmaf(c1, P0.z, fmaf(c0, P0.x, vs[q][0].x));
      vs[q][0].y = fmaf(c1, P0.w, fmaf(c0, P0.y, vs[q][0].y));
      vs[q][1].x = fmaf(c1, P1.z, fmaf(c0, P1.x, vs[q][1].x));
      vs[q][1].y = fmaf(c1, P1.w, fmaf(c0, P1.y, vs[q][1].y));
      vs[q][2].x = fmaf(c1, P2.z, fmaf(c0, P2.x, vs[q][2].x));
      vs[q][2].y = fmaf(c1, P2.w, fmaf(c0, P2.y, vs[q][2].y));
    }
  }

  float y[2][6];
#pragma unroll
  for (int q=0;q<2;q++)
#pragma unroll
    for (int i=0;i<6;i++) y[q][i] = 0.f;

#pragma unroll 2
  for (int np=0; np<12; np++){
    const float4 wp = pk4[(17+np)*VH + vh];  // W(2np): xy, W(2np+1): zw
#pragma unroll
    for (int half=0; half<2; half++){
      const int n = 2*np + half;
      const float wx = half ? wp.z : wp.x;
      const float wy = half ? wp.w : wp.y;
#pragma unroll
      for (int q=0;q<2;q++){
        const float* __restrict__ an = Ag + n*24 + q*12;   // block-uniform -> s_load
        float tt;
        tt = fmaf(an[2], vs[q][2].x, fmaf(an[1], vs[q][1].x, fmaf(an[0], vs[q][0].x, an[3])));
        y[q][0] = fmaf(wx, tt, y[q][0]);
        tt = fmaf(an[2], vs[q][2].y, fmaf(an[1], vs[q][1].y, fmaf(an[0], vs[q][0].y, an[3])));
        y[q][1] = fmaf(wy, tt, y[q][1]);
        tt = fmaf(an[6], vs[q][2].x, fmaf(an[5], vs[q][1].x, fmaf(an[4], vs[q][0].x, an[7])));
        y[q][2] = fmaf(wx, tt, y[q][2]);
        tt = fmaf(an[6], vs[q][2].y, fmaf(an[5], vs[q][1].y, fmaf(an[4], vs[q][0].y, an[7])));
        y[q][3] = fmaf(wy, tt, y[q][3]);
        tt = fmaf(an[10], vs[q][2].x, fmaf(an[9], vs[q][1].x, fmaf(an[8], vs[q][0].x, an[11])));
        y[q][4] = fmaf(wx, tt, y[q][4]);
        tt = fmaf(an[10], vs[q][2].y, fmaf(an[9], vs[q][1].y, fmaf(an[8], vs[q][0].y, an[11])));
        y[q][5] = fmaf(wy, tt, y[q][5]);
      }
    }
  }

  const int v0 = 2*vh;
#pragma unroll
  for (int q=0;q<2;q++){
    const float t0 = bs[q*16+11], t1 = bs[q*16+12], t2 = bs[q*16+13];
    const int b = bg*2 + q;
    float2* __restrict__ o2 = (float2*)(out + (b*V + v0)*3);
    o2[0] = make_float2(y[q][0]+t0, y[q][2]+t1);
    o2[1] = make_float2(y[q][4]+t2, y[q][1]+t0);
    o2[2] = make_float2(y[q][3]+t1, y[q][5]+t2);
  }
}

extern "C" void kernel_launch(void* const* d_in, const int* in_sizes, int n_in,
                              void* d_out, int out_size, void* d_ws, size_t ws_size,
                              hipStream_t stream)
{
  const float* betas     = (const float*)d_in[0];
  const float* body_pose = (const float*)d_in[1];
  const float* go        = (const float*)d_in[2];
  const float* transl    = (const float*)d_in[3];
  const float* sdirs     = (const float*)d_in[4];
  const float* vtempl    = (const float*)d_in[5];
  const float* Jr        = (const float*)d_in[6];
  const float* lw        = (const float*)d_in[7];
  float* wsf = (float*)d_ws;
  float* out = (float*)d_out;

  hipLaunchKernelGGL(prepjreg_k, dim3(PREP4_BLOCKS + JREG_BLOCKS), dim3(256), 0, stream,
                     sdirs, vtempl, lw, Jr, (float4*)(wsf+PK_OFF), wsf+JP_OFF);
  hipLaunchKernelGGL(batch_k, dim3(BATCH), dim3(64), 0, stream,
                     betas, body_pose, go, transl, wsf+JP_OFF,
                     wsf+A_OFF, wsf+BS_OFF, out + BATCH*V*3);
  hipLaunchKernelGGL(main_k, dim3((VH+255)/256, BATCH/2), dim3(256), 0, stream,
                     wsf+A_OFF, wsf+BS_OFF, (const float4*)(wsf+PK_OFF), out);
}